// Round 4
// baseline (237.647 us; speedup 1.0000x reference)
//
#include <hip/hip_runtime.h>

#define GROUP 8
#define BS 4096
#define CH 512
#define PW 32        // base panel width
#define NPANEL 16

typedef __attribute__((ext_vector_type(4))) float f32x4;
typedef __attribute__((ext_vector_type(8))) short bf16x8;
typedef unsigned short u16;

static __device__ __forceinline__ u16 f2bf(float f) {
    unsigned int u = __builtin_bit_cast(unsigned int, f);
    u += 0x7FFFu + ((u >> 16) & 1u);   // round-to-nearest-even
    return (u16)(u >> 16);
}
static __device__ __forceinline__ float bf2f(u16 h) {
    return __builtin_bit_cast(float, (unsigned int)h << 16);
}
// split fp32[8] -> bf16 hi + bf16 lo (hi+lo ~ 16 mantissa bits)
static __device__ __forceinline__ void split8(const float* v, bf16x8& h, bf16x8& l) {
#pragma unroll
    for (int j = 0; j < 8; ++j) {
        u16 hu = f2bf(v[j]);
        h[j] = (short)hu;
        l[j] = (short)f2bf(v[j] - bf2f(hu));
    }
}
#define MFMA(a, b, c) __builtin_amdgcn_mfma_f32_16x16x32_bf16(a, b, c, 0, 0, 0)

// ---------------------------------------------------------------------------
// Kernel 1: transpose weight  wt[g][i][c] = w[g][c][i]  (v_i contiguous rows)
// ---------------------------------------------------------------------------
__global__ __launch_bounds__(256) void k_transpose(const float* __restrict__ w,
                                                   float* __restrict__ wt) {
    __shared__ float tile[64][65];
    int b = blockIdx.x;
    int g = b >> 6;
    int tt = b & 63;
    int i0 = (tt & 7) * 64;
    int c0 = (tt >> 3) * 64;
    const float* wg = w + (size_t)g * CH * CH;
    float* wtg = wt + (size_t)g * CH * CH;
    int col = threadIdx.x & 63;
    int r4  = threadIdx.x >> 6;
#pragma unroll
    for (int it = 0; it < 16; ++it) {
        int r = it * 4 + r4;
        tile[r][col] = wg[(size_t)(c0 + r) * CH + i0 + col];
    }
    __syncthreads();
#pragma unroll
    for (int it = 0; it < 16; ++it) {
        int r = it * 4 + r4;
        wtg[(size_t)(i0 + r) * CH + c0 + col] = tile[col][r];
    }
}

// ---------------------------------------------------------------------------
// Kernel 2: per-32-panel prep (verified round-3 math). Outputs:
//   Yh/Yl  [g][i_global=p*32+i][c]  bf16 hi/lo of reflector rows
//   Mth/Mtl[g][c][i_global]        bf16 hi/lo of M = T*Y (col-major in i)
// ---------------------------------------------------------------------------
__global__ __launch_bounds__(256) void k_panelprep(const float* __restrict__ wt,
                                                   u16* __restrict__ Yh,
                                                   u16* __restrict__ Yl,
                                                   u16* __restrict__ Mth,
                                                   u16* __restrict__ Mtl) {
    __shared__ float Ylds[PW][516];
    __shared__ float Sp[4][PW][36];
    __shared__ float S_ls[PW][36];
    __shared__ float T_ls[PW][36];
    __shared__ float betaL[PW];

    int t    = threadIdx.x;
    int lane = t & 63;
    int w    = t >> 6;
    int fr   = lane & 15;
    int kg   = lane >> 4;
    int g    = blockIdx.x >> 4;
    int p    = blockIdx.x & 15;

    const float* Ysrc = wt + ((size_t)g * CH + p * PW) * CH;

    for (int idx4 = t; idx4 < PW * 128; idx4 += 256) {
        int r = idx4 >> 7, c4 = idx4 & 127;
        *(float4*)&Ylds[r][c4 * 4] = *(const float4*)(Ysrc + (size_t)r * CH + c4 * 4);
    }
    __syncthreads();

    // ---- S = Y Y^T via split MFMA; wave w covers kk = 4w..4w+3 ----
    {
        f32x4 sacc[2][2];
#pragma unroll
        for (int a = 0; a < 2; ++a)
#pragma unroll
            for (int b = 0; b < 2; ++b)
#pragma unroll
                for (int z = 0; z < 4; ++z) sacc[a][b][z] = 0.f;
#pragma unroll
        for (int kki = 0; kki < 4; ++kki) {
            int kk = 4 * w + kki;
            bf16x8 fh[2], fl[2];
#pragma unroll
            for (int h = 0; h < 2; ++h) {
                float a8[8];
                const float* src = &Ylds[h * 16 + fr][kk * 32 + kg * 8];
#pragma unroll
                for (int j = 0; j < 8; ++j) a8[j] = src[j];
                split8(a8, fh[h], fl[h]);
            }
#pragma unroll
            for (int a = 0; a < 2; ++a)
#pragma unroll
                for (int b = 0; b < 2; ++b) {
                    sacc[a][b] = MFMA(fh[a], fh[b], sacc[a][b]);
                    sacc[a][b] = MFMA(fh[a], fl[b], sacc[a][b]);
                    sacc[a][b] = MFMA(fl[a], fh[b], sacc[a][b]);
                }
        }
#pragma unroll
        for (int a = 0; a < 2; ++a)
#pragma unroll
            for (int b = 0; b < 2; ++b)
#pragma unroll
                for (int j = 0; j < 4; ++j)
                    Sp[w][a * 16 + kg * 4 + j][b * 16 + fr] = sacc[a][b][j];
    }
    __syncthreads();
    for (int idx = t; idx < PW * PW; idx += 256) {
        int r = idx >> 5, c = idx & 31;
        S_ls[r][c] = Sp[0][r][c] + Sp[1][r][c] + Sp[2][r][c] + Sp[3][r][c];
    }
    __syncthreads();
    if (t < PW) betaL[t] = 2.0f / S_ls[t][t];
    for (int idx = t; idx < PW * 36; idx += 256) ((float*)T_ls)[idx] = 0.f;
    __syncthreads();
    if (t < PW) T_ls[t][t] = betaL[t];
    __syncthreads();
    for (int k = 1; k < PW; ++k) {
        if (t < k) {
            float acc = 0.f;
            for (int j = t; j < k; ++j) acc += T_ls[t][j] * S_ls[j][k];
            T_ls[t][k] = -betaL[k] * acc;
        }
        __syncthreads();
    }

    // ---- M^T = Y^T * T^T (512x32, K=32): wave w covers rf = 8w..8w+7 ----
    bf16x8 tbh[2], tbl[2];
#pragma unroll
    for (int cf = 0; cf < 2; ++cf) {
        float t8[8];
        const float* src = &T_ls[cf * 16 + fr][kg * 8];
#pragma unroll
        for (int j = 0; j < 8; ++j) t8[j] = src[j];
        split8(t8, tbh[cf], tbl[cf]);
    }
#pragma unroll
    for (int rfi = 0; rfi < 8; ++rfi) {
        int rf = 8 * w + rfi;
        float a8[8];
#pragma unroll
        for (int j = 0; j < 8; ++j) a8[j] = Ylds[kg * 8 + j][rf * 16 + fr];
        bf16x8 ah, al;
        split8(a8, ah, al);
#pragma unroll
        for (int cf = 0; cf < 2; ++cf) {
            f32x4 m;
#pragma unroll
            for (int z = 0; z < 4; ++z) m[z] = 0.f;
            m = MFMA(ah, tbh[cf], m);
            m = MFMA(ah, tbl[cf], m);
            m = MFMA(al, tbh[cf], m);
#pragma unroll
            for (int j = 0; j < 4; ++j) {
                int c = rf * 16 + kg * 4 + j;
                int i = cf * 16 + fr;
                size_t off = ((size_t)g * CH + c) * CH + (p * PW + i);  // [g][c][i_glob]
                u16 hu = f2bf(m[j]);
                Mth[off] = hu;
                Mtl[off] = f2bf(m[j] - bf2f(hu));
            }
        }
    }

    // ---- export Y panel bf16 hi/lo ----
    for (int idx = t; idx < PW * CH; idx += 256) {
        int r = idx >> 9, c = idx & 511;
        float v = Ylds[r][c];
        size_t off = ((size_t)g * CH + p * PW + r) * CH + c;
        u16 hu = f2bf(v);
        Yh[off] = hu;
        Yl[off] = f2bf(v - bf2f(hu));
    }
}

// ---------------------------------------------------------------------------
// Kernel 3 (x4 levels): WY merge.  M_top' = M_top - (M_top Y_bot^T) M_bot.
// Level W: 64 blocks (g x 8 strips of 32 top-rows), 4 waves.
// In-place on Mth/Mtl: each block writes ONLY its own strip; bottoms are
// read-only at this level -> race-free.
// ---------------------------------------------------------------------------
template<int W>
__global__ __launch_bounds__(256) void k_combine(const u16* __restrict__ Yh,
                                                 const u16* __restrict__ Yl,
                                                 u16* __restrict__ Mth,
                                                 u16* __restrict__ Mtl) {
    __shared__ u16 MAh[32][520];
    __shared__ u16 MAl[32][520];
    __shared__ float Cl[32][260];

    int t = threadIdx.x, lane = t & 63, wv = t >> 6;
    int fr = lane & 15, kg = lane >> 4;
    int g  = blockIdx.x >> 3;
    int sg = blockIdx.x & 7;
    constexpr int NSTRIP = W / 32;
    int q  = sg / NSTRIP, rs = sg % NSTRIP;
    int i_top0 = 2 * q * W + rs * 32;
    int i_bot0 = 2 * q * W + W;

    const u16* Yh_g = Yh + (size_t)g * CH * CH;
    const u16* Yl_g = Yl + (size_t)g * CH * CH;
    u16* Mth_g = Mth + (size_t)g * CH * CH;
    u16* Mtl_g = Mtl + (size_t)g * CH * CH;

    // ---- stage M_A strip, transposed to row-major MA[i][c] ----
    for (int idx = t; idx < 2048; idx += 256) {
        int c = idx >> 2, ch = idx & 3;
        bf16x8 hv = *(const bf16x8*)(Mth_g + (size_t)c * CH + i_top0 + ch * 8);
        bf16x8 lv = *(const bf16x8*)(Mtl_g + (size_t)c * CH + i_top0 + ch * 8);
#pragma unroll
        for (int j = 0; j < 8; ++j) {
            MAh[ch * 8 + j][c] = (u16)hv[j];
            MAl[ch * 8 + j][c] = (u16)lv[j];
        }
    }
    __syncthreads();

    // ---- C[i][jb] = sum_c MA[i][c] Ybot[jb][c]   (32 x W, K=512) ----
    constexpr int NF = W / 16;
    constexpr int CPW = (NF + 3) / 4;
    f32x4 accC[2][CPW];
#pragma unroll
    for (int mi = 0; mi < 2; ++mi)
#pragma unroll
        for (int nfi = 0; nfi < CPW; ++nfi)
#pragma unroll
            for (int z = 0; z < 4; ++z) accC[mi][nfi][z] = 0.f;

    for (int ks = 0; ks < 16; ++ks) {
        bf16x8 ah[2], al[2];
#pragma unroll
        for (int mi = 0; mi < 2; ++mi) {
            ah[mi] = *(const bf16x8*)&MAh[mi * 16 + fr][ks * 32 + kg * 8];
            al[mi] = *(const bf16x8*)&MAl[mi * 16 + fr][ks * 32 + kg * 8];
        }
#pragma unroll
        for (int nfi = 0; nfi < CPW; ++nfi) {
            int nf = wv + 4 * nfi;
            if (nf < NF) {
                size_t yo = (size_t)(i_bot0 + nf * 16 + fr) * CH + ks * 32 + kg * 8;
                bf16x8 bh = *(const bf16x8*)(Yh_g + yo);
                bf16x8 bl = *(const bf16x8*)(Yl_g + yo);
#pragma unroll
                for (int mi = 0; mi < 2; ++mi) {
                    accC[mi][nfi] = MFMA(ah[mi], bh, accC[mi][nfi]);
                    accC[mi][nfi] = MFMA(ah[mi], bl, accC[mi][nfi]);
                    accC[mi][nfi] = MFMA(al[mi], bh, accC[mi][nfi]);
                }
            }
        }
    }
#pragma unroll
    for (int mi = 0; mi < 2; ++mi)
#pragma unroll
        for (int nfi = 0; nfi < CPW; ++nfi) {
            int nf = wv + 4 * nfi;
            if (nf < NF)
#pragma unroll
                for (int jj = 0; jj < 4; ++jj)
                    Cl[mi * 16 + kg * 4 + jj][nf * 16 + fr] = accC[mi][nfi][jj];
        }
    __syncthreads();

    // ---- U[i][c] = sum_j C[i][j] MB[j][c]  (32 x 512, K=W); M' = MA - U ----
    f32x4 accU[2][8];
#pragma unroll
    for (int mi = 0; mi < 2; ++mi)
#pragma unroll
        for (int ni = 0; ni < 8; ++ni)
#pragma unroll
            for (int z = 0; z < 4; ++z) accU[mi][ni][z] = 0.f;

    for (int ks2 = 0; ks2 < W / 32; ++ks2) {
        bf16x8 ah2[2], al2[2];
#pragma unroll
        for (int mi = 0; mi < 2; ++mi) {
            float a8[8];
#pragma unroll
            for (int j = 0; j < 8; ++j) a8[j] = Cl[mi * 16 + fr][ks2 * 32 + kg * 8 + j];
            split8(a8, ah2[mi], al2[mi]);
        }
#pragma unroll
        for (int ni = 0; ni < 8; ++ni) {
            int c = (wv * 8 + ni) * 16 + fr;
            size_t mo = (size_t)c * CH + i_bot0 + ks2 * 32 + kg * 8;
            bf16x8 bh = *(const bf16x8*)(Mth_g + mo);
            bf16x8 bl = *(const bf16x8*)(Mtl_g + mo);
#pragma unroll
            for (int mi = 0; mi < 2; ++mi) {
                accU[mi][ni] = MFMA(ah2[mi], bh, accU[mi][ni]);
                accU[mi][ni] = MFMA(ah2[mi], bl, accU[mi][ni]);
                accU[mi][ni] = MFMA(al2[mi], bh, accU[mi][ni]);
            }
        }
    }
    // subtract & write back in place into MA (element ownership is unique)
#pragma unroll
    for (int mi = 0; mi < 2; ++mi)
#pragma unroll
        for (int ni = 0; ni < 8; ++ni) {
            int c = (wv * 8 + ni) * 16 + fr;
#pragma unroll
            for (int jj = 0; jj < 4; ++jj) {
                int il = mi * 16 + kg * 4 + jj;
                float ma = bf2f(MAh[il][c]) + bf2f(MAl[il][c]);
                float m2 = ma - accU[mi][ni][jj];
                u16 hu = f2bf(m2);
                MAh[il][c] = hu;
                MAl[il][c] = f2bf(m2 - bf2f(hu));
            }
        }
    __syncthreads();

    // ---- coalesced store back to [c][i] layout ----
    for (int idx = t; idx < 2048; idx += 256) {
        int c = idx >> 2, ch = idx & 3;
        bf16x8 hv, lv;
#pragma unroll
        for (int j = 0; j < 8; ++j) {
            hv[j] = (short)MAh[ch * 8 + j][c];
            lv[j] = (short)MAl[ch * 8 + j][c];
        }
        *(bf16x8*)(Mth_g + (size_t)c * CH + i_top0 + ch * 8) = hv;
        *(bf16x8*)(Mtl_g + (size_t)c * CH + i_top0 + ch * 8) = lv;
    }
}

// ---------------------------------------------------------------------------
// Kernel 4: Q = I - A*M where A[c][i] = w[g][c][i] (original w, no transpose!)
// and B[k=i][n=d] = M[i][d] read from Mt layout. 128x128 tiles, K=512.
// ---------------------------------------------------------------------------
__global__ __launch_bounds__(256) void k_qbuild2(const float* __restrict__ w,
                                                 const u16* __restrict__ Mth,
                                                 const u16* __restrict__ Mtl,
                                                 float* __restrict__ Q) {
    int t = threadIdx.x, lane = t & 63, wv = t >> 6;
    int fr = lane & 15, kg = lane >> 4;
    int g  = blockIdx.x >> 4;
    int tm = (blockIdx.x >> 2) & 3, tn = blockIdx.x & 3;
    int wr = wv >> 1, wc = wv & 1;
    int c0 = tm * 128 + wr * 64;
    int d0 = tn * 128 + wc * 64;

    const float* wg = w + (size_t)g * CH * CH;
    const u16* Mth_g = Mth + (size_t)g * CH * CH;
    const u16* Mtl_g = Mtl + (size_t)g * CH * CH;

    f32x4 acc[4][4];
#pragma unroll
    for (int mi = 0; mi < 4; ++mi)
#pragma unroll
        for (int ni = 0; ni < 4; ++ni)
#pragma unroll
            for (int z = 0; z < 4; ++z) acc[mi][ni][z] = 0.f;

    for (int ks = 0; ks < 16; ++ks) {
        bf16x8 ah[4], al[4], bh[4], bl[4];
#pragma unroll
        for (int mi = 0; mi < 4; ++mi) {
            const float* src = wg + (size_t)(c0 + mi * 16 + fr) * CH + ks * 32 + kg * 8;
            float4 v0 = *(const float4*)src;
            float4 v1 = *(const float4*)(src + 4);
            float a8[8] = {v0.x, v0.y, v0.z, v0.w, v1.x, v1.y, v1.z, v1.w};
            split8(a8, ah[mi], al[mi]);
        }
#pragma unroll
        for (int ni = 0; ni < 4; ++ni) {
            size_t mo = (size_t)(d0 + ni * 16 + fr) * CH + ks * 32 + kg * 8;
            bh[ni] = *(const bf16x8*)(Mth_g + mo);
            bl[ni] = *(const bf16x8*)(Mtl_g + mo);
        }
#pragma unroll
        for (int mi = 0; mi < 4; ++mi)
#pragma unroll
            for (int ni = 0; ni < 4; ++ni) {
                acc[mi][ni] = MFMA(ah[mi], bh[ni], acc[mi][ni]);
                acc[mi][ni] = MFMA(ah[mi], bl[ni], acc[mi][ni]);
                acc[mi][ni] = MFMA(al[mi], bh[ni], acc[mi][ni]);
            }
    }
#pragma unroll
    for (int mi = 0; mi < 4; ++mi)
#pragma unroll
        for (int ni = 0; ni < 4; ++ni)
#pragma unroll
            for (int jj = 0; jj < 4; ++jj) {
                int c = c0 + mi * 16 + kg * 4 + jj;
                int d = d0 + ni * 16 + fr;
                float v = ((c == d) ? 1.0f : 0.0f) - acc[mi][ni][jj];
                Q[((size_t)g * CH + c) * CH + d] = v;
            }
}

// ---------------------------------------------------------------------------
// Kernel 5: out[g] = x[g] (4096x512) @ Q[g] (512x512), bf16 MFMA, fp32 acc.
// ---------------------------------------------------------------------------
#define BM 128
#define BN 128
#define BK 32
#define LDP 40

__global__ __launch_bounds__(256) void k_gemm(const float* __restrict__ x,
                                              const float* __restrict__ Q,
                                              float* __restrict__ out) {
    __shared__ u16 Al[BM * LDP];
    __shared__ u16 Bl[BN * LDP];

    int bid = blockIdx.x;
    int g  = bid >> 7;
    int tn = (bid >> 5) & 3;
    int tm = bid & 31;

    int t    = threadIdx.x;
    int lane = t & 63;
    int w    = t >> 6;
    int wr   = w >> 1, wc = w & 1;

    const float* xg = x + (size_t)g * BS * CH + (size_t)tm * BM * CH;
    const float* Qg = Q + (size_t)g * CH * CH + (size_t)tn * BN;
    float* og = out + (size_t)g * BS * CH + (size_t)tm * BM * CH + (size_t)tn * BN;

    f32x4 acc[4][4];
#pragma unroll
    for (int mi = 0; mi < 4; ++mi)
#pragma unroll
        for (int ni = 0; ni < 4; ++ni)
#pragma unroll
            for (int z = 0; z < 4; ++z) acc[mi][ni][z] = 0.f;

    int a_k4 = t & 7;
    int a_r  = t >> 3;
    int b_n  = t & 127;
    int b_kh = t >> 7;

    int fr = lane & 15, kg = lane >> 4;

    typedef __attribute__((ext_vector_type(8))) unsigned short u16x8;
    for (int ks = 0; ks < CH / BK; ++ks) {
        int k0 = ks * BK;
        __syncthreads();
#pragma unroll
        for (int rr = 0; rr < 4; ++rr) {
            int r = a_r + 32 * rr;
            float4 v = *(const float4*)(xg + (size_t)r * CH + k0 + a_k4 * 4);
            ushort4 h;
            h.x = f2bf(v.x); h.y = f2bf(v.y); h.z = f2bf(v.z); h.w = f2bf(v.w);
            *(ushort4*)(&Al[r * LDP + a_k4 * 4]) = h;
        }
        {
            u16x8 lo, hi;
#pragma unroll
            for (int j = 0; j < 8; ++j)
                lo[j] = f2bf(Qg[(size_t)(k0 + b_kh * 16 + j) * CH + b_n]);
#pragma unroll
            for (int j = 0; j < 8; ++j)
                hi[j] = f2bf(Qg[(size_t)(k0 + b_kh * 16 + 8 + j) * CH + b_n]);
            *(u16x8*)(&Bl[b_n * LDP + b_kh * 16]) = lo;
            *(u16x8*)(&Bl[b_n * LDP + b_kh * 16 + 8]) = hi;
        }
        __syncthreads();
        bf16x8 af[4], bfr[4];
#pragma unroll
        for (int mi = 0; mi < 4; ++mi)
            af[mi] = *(const bf16x8*)(&Al[(wr * 64 + mi * 16 + fr) * LDP + kg * 8]);
#pragma unroll
        for (int ni = 0; ni < 4; ++ni)
            bfr[ni] = *(const bf16x8*)(&Bl[(wc * 64 + ni * 16 + fr) * LDP + kg * 8]);
#pragma unroll
        for (int mi = 0; mi < 4; ++mi)
#pragma unroll
            for (int ni = 0; ni < 4; ++ni)
                acc[mi][ni] = MFMA(af[mi], bfr[ni], acc[mi][ni]);
    }

    int rg = lane >> 4;
#pragma unroll
    for (int mi = 0; mi < 4; ++mi)
#pragma unroll
        for (int ni = 0; ni < 4; ++ni)
#pragma unroll
            for (int rj = 0; rj < 4; ++rj) {
                int grow = wr * 64 + mi * 16 + rg * 4 + rj;
                int gcol = wc * 64 + ni * 16 + fr;
                og[(size_t)grow * CH + gcol] = acc[mi][ni][rj];
            }
}

// ---------------------------------------------------------------------------
extern "C" void kernel_launch(void* const* d_in, const int* in_sizes, int n_in,
                              void* d_out, int out_size, void* d_ws, size_t ws_size,
                              hipStream_t stream) {
    const float* x = (const float*)d_in[0];   // (8, 4096, 512)
    const float* w = (const float*)d_in[1];   // (8, 512, 512)
    float* out = (float*)d_out;

    // scratch carved from d_out (64 MiB; dead before k_gemm writes it):
    char* ob = (char*)d_out;
    float* wt  = (float*)ob;                       // [0, 8MB)
    u16*   Yh  = (u16*)(ob + (8u  << 20));         // [8, 12)
    u16*   Yl  = (u16*)(ob + (12u << 20));         // [12, 16)
    u16*   Mth = (u16*)(ob + (16u << 20));         // [16, 20)
    u16*   Mtl = (u16*)(ob + (20u << 20));         // [20, 24)
    float* Q   = (float*)d_ws;                     // 8 MB

    k_transpose<<<dim3(512), dim3(256), 0, stream>>>(w, wt);
    k_panelprep<<<dim3(128), dim3(256), 0, stream>>>(wt, Yh, Yl, Mth, Mtl);
    k_combine<32><<<dim3(64), dim3(256), 0, stream>>>(Yh, Yl, Mth, Mtl);
    k_combine<64><<<dim3(64), dim3(256), 0, stream>>>(Yh, Yl, Mth, Mtl);
    k_combine<128><<<dim3(64), dim3(256), 0, stream>>>(Yh, Yl, Mth, Mtl);
    k_combine<256><<<dim3(64), dim3(256), 0, stream>>>(Yh, Yl, Mth, Mtl);
    k_qbuild2<<<dim3(128), dim3(256), 0, stream>>>(w, Mth, Mtl, Q);
    k_gemm<<<dim3(1024), dim3(256), 0, stream>>>(x, Q, out);
}

// Round 5
// 213.166 us; speedup vs baseline: 1.1148x; 1.1148x over previous
//
#include <hip/hip_runtime.h>

#define GROUP 8
#define BS 4096
#define CH 512
#define PW 32        // base panel width
#define NPANEL 16

typedef __attribute__((ext_vector_type(4))) float f32x4;
typedef __attribute__((ext_vector_type(8))) short bf16x8;
typedef __attribute__((ext_vector_type(8))) unsigned short u16x8;
typedef unsigned short u16;

static __device__ __forceinline__ u16 f2bf(float f) {
    unsigned int u = __builtin_bit_cast(unsigned int, f);
    u += 0x7FFFu + ((u >> 16) & 1u);   // round-to-nearest-even
    return (u16)(u >> 16);
}
static __device__ __forceinline__ float bf2f(u16 h) {
    return __builtin_bit_cast(float, (unsigned int)h << 16);
}
// split fp32[8] -> bf16 hi + bf16 lo (hi+lo ~ 16 mantissa bits)
static __device__ __forceinline__ void split8(const float* v, bf16x8& h, bf16x8& l) {
#pragma unroll
    for (int j = 0; j < 8; ++j) {
        u16 hu = f2bf(v[j]);
        h[j] = (short)hu;
        l[j] = (short)f2bf(v[j] - bf2f(hu));
    }
}
#define MFMA(a, b, c) __builtin_amdgcn_mfma_f32_16x16x32_bf16(a, b, c, 0, 0, 0)

// ---------------------------------------------------------------------------
// Kernel 1: per-32-panel prep (verified math; transpose fused into staging).
// 128 blocks x 256 thr. Outputs:
//   Yh/Yl  [g][i_glob=p*32+i][c]  bf16 hi/lo reflector rows
//   Mth/Mtl[g][c][i_glob]         bf16 hi/lo of M = T*Y
// ---------------------------------------------------------------------------
__global__ __launch_bounds__(256) void k_panelprep(const float* __restrict__ w,
                                                   u16* __restrict__ Yh,
                                                   u16* __restrict__ Yl,
                                                   u16* __restrict__ Mth,
                                                   u16* __restrict__ Mtl) {
    __shared__ float Ylds[PW][516];
    __shared__ float Sp[4][PW][36];
    __shared__ float S_ls[PW][36];
    __shared__ float T_ls[PW][36];
    __shared__ float betaL[PW];

    int t    = threadIdx.x;
    int lane = t & 63;
    int wv   = t >> 6;
    int fr   = lane & 15;
    int kg   = lane >> 4;
    int g    = blockIdx.x >> 4;
    int p    = blockIdx.x & 15;
    int i0   = p * PW;

    // ---- stage Y[i][c] = w[g][c][i0+i]  (transpose-read, 32x512) ----
    const float* wg = w + (size_t)g * CH * CH;
    for (int idx4 = t; idx4 < 4096; idx4 += 256) {
        int c = idx4 >> 3, f4 = idx4 & 7;
        float4 v = *(const float4*)(wg + (size_t)c * CH + i0 + f4 * 4);
        Ylds[f4 * 4 + 0][c] = v.x;
        Ylds[f4 * 4 + 1][c] = v.y;
        Ylds[f4 * 4 + 2][c] = v.z;
        Ylds[f4 * 4 + 3][c] = v.w;
    }
    __syncthreads();

    // ---- S = Y Y^T via split MFMA; wave wv covers kk = 4wv..4wv+3 ----
    {
        f32x4 sacc[2][2];
#pragma unroll
        for (int a = 0; a < 2; ++a)
#pragma unroll
            for (int b = 0; b < 2; ++b)
#pragma unroll
                for (int z = 0; z < 4; ++z) sacc[a][b][z] = 0.f;
#pragma unroll
        for (int kki = 0; kki < 4; ++kki) {
            int kk = 4 * wv + kki;
            bf16x8 fh[2], fl[2];
#pragma unroll
            for (int h = 0; h < 2; ++h) {
                float a8[8];
                const float* src = &Ylds[h * 16 + fr][kk * 32 + kg * 8];
#pragma unroll
                for (int j = 0; j < 8; ++j) a8[j] = src[j];
                split8(a8, fh[h], fl[h]);
            }
#pragma unroll
            for (int a = 0; a < 2; ++a)
#pragma unroll
                for (int b = 0; b < 2; ++b) {
                    sacc[a][b] = MFMA(fh[a], fh[b], sacc[a][b]);
                    sacc[a][b] = MFMA(fh[a], fl[b], sacc[a][b]);
                    sacc[a][b] = MFMA(fl[a], fh[b], sacc[a][b]);
                }
        }
#pragma unroll
        for (int a = 0; a < 2; ++a)
#pragma unroll
            for (int b = 0; b < 2; ++b)
#pragma unroll
                for (int j = 0; j < 4; ++j)
                    Sp[wv][a * 16 + kg * 4 + j][b * 16 + fr] = sacc[a][b][j];
    }
    __syncthreads();
    for (int idx = t; idx < PW * PW; idx += 256) {
        int r = idx >> 5, c = idx & 31;
        S_ls[r][c] = Sp[0][r][c] + Sp[1][r][c] + Sp[2][r][c] + Sp[3][r][c];
    }
    __syncthreads();
    if (t < PW) betaL[t] = 2.0f / S_ls[t][t];
    for (int idx = t; idx < PW * 36; idx += 256) ((float*)T_ls)[idx] = 0.f;
    __syncthreads();
    if (t < PW) T_ls[t][t] = betaL[t];
    __syncthreads();
    for (int k = 1; k < PW; ++k) {
        if (t < k) {
            float acc = 0.f;
            for (int j = t; j < k; ++j) acc += T_ls[t][j] * S_ls[j][k];
            T_ls[t][k] = -betaL[k] * acc;
        }
        __syncthreads();
    }

    // ---- M^T = Y^T * T^T (512x32, K=32): wave wv covers rf = 8wv..8wv+7 ----
    bf16x8 tbh[2], tbl[2];
#pragma unroll
    for (int cf = 0; cf < 2; ++cf) {
        float t8[8];
        const float* src = &T_ls[cf * 16 + fr][kg * 8];
#pragma unroll
        for (int j = 0; j < 8; ++j) t8[j] = src[j];
        split8(t8, tbh[cf], tbl[cf]);
    }
#pragma unroll
    for (int rfi = 0; rfi < 8; ++rfi) {
        int rf = 8 * wv + rfi;
        float a8[8];
#pragma unroll
        for (int j = 0; j < 8; ++j) a8[j] = Ylds[kg * 8 + j][rf * 16 + fr];
        bf16x8 ah, al;
        split8(a8, ah, al);
#pragma unroll
        for (int cf = 0; cf < 2; ++cf) {
            f32x4 m;
#pragma unroll
            for (int z = 0; z < 4; ++z) m[z] = 0.f;
            m = MFMA(ah, tbh[cf], m);
            m = MFMA(ah, tbl[cf], m);
            m = MFMA(al, tbh[cf], m);
#pragma unroll
            for (int j = 0; j < 4; ++j) {
                int c = rf * 16 + kg * 4 + j;
                int i = cf * 16 + fr;
                size_t off = ((size_t)g * CH + c) * CH + (i0 + i);  // [g][c][i_glob]
                u16 hu = f2bf(m[j]);
                Mth[off] = hu;
                Mtl[off] = f2bf(m[j] - bf2f(hu));
            }
        }
    }

    // ---- export Y panel bf16 hi/lo ----
    for (int idx = t; idx < PW * CH; idx += 256) {
        int r = idx >> 9, c = idx & 511;
        float v = Ylds[r][c];
        size_t off = ((size_t)g * CH + i0 + r) * CH + c;
        u16 hu = f2bf(v);
        Yh[off] = hu;
        Yl[off] = f2bf(v - bf2f(hu));
    }
}

// ---------------------------------------------------------------------------
// Kernel 2 (x4 levels): WY merge.  M_top' = M_top - (M_top Y_bot^T) M_bot.
// 128 blocks (g x 16 strips of 16 top-rows), 4 waves. In-place, race-free
// (tops written disjoint; bottoms read-only at this level).
// ---------------------------------------------------------------------------
template<int W>
__global__ __launch_bounds__(256) void k_combine(const u16* __restrict__ Yh,
                                                 const u16* __restrict__ Yl,
                                                 u16* __restrict__ Mth,
                                                 u16* __restrict__ Mtl) {
    __shared__ u16 MAh[16][520];
    __shared__ u16 MAl[16][520];
    __shared__ float Cl[16][260];

    int t = threadIdx.x, lane = t & 63, wv = t >> 6;
    int fr = lane & 15, kg = lane >> 4;
    int g  = blockIdx.x >> 4;
    int sg = blockIdx.x & 15;
    constexpr int SP = W / 16;            // 16-row strips per pair-top
    int q  = sg / SP, rs = sg % SP;
    int i_top0 = 2 * q * W + rs * 16;
    int i_bot0 = 2 * q * W + W;

    const u16* Yh_g = Yh + (size_t)g * CH * CH;
    const u16* Yl_g = Yl + (size_t)g * CH * CH;
    u16* Mth_g = Mth + (size_t)g * CH * CH;
    u16* Mtl_g = Mtl + (size_t)g * CH * CH;

    // ---- stage M_A strip transposed to row-major MA[i][c] (16 x 512) ----
    for (int idx = t; idx < 1024; idx += 256) {
        int c = idx >> 1, ch = idx & 1;
        bf16x8 hv = *(const bf16x8*)(Mth_g + (size_t)c * CH + i_top0 + ch * 8);
        bf16x8 lv = *(const bf16x8*)(Mtl_g + (size_t)c * CH + i_top0 + ch * 8);
#pragma unroll
        for (int j = 0; j < 8; ++j) {
            MAh[ch * 8 + j][c] = (u16)hv[j];
            MAl[ch * 8 + j][c] = (u16)lv[j];
        }
    }
    __syncthreads();

    // ---- C[i][jb] = sum_c MA[i][c] Ybot[jb][c]   (16 x W, K=512) ----
    constexpr int NF = W / 16;
    constexpr int CPW = (NF + 3) / 4;
    f32x4 accC[CPW];
#pragma unroll
    for (int nfi = 0; nfi < CPW; ++nfi)
#pragma unroll
        for (int z = 0; z < 4; ++z) accC[nfi][z] = 0.f;

    for (int ks = 0; ks < 16; ++ks) {
        bf16x8 ah = *(const bf16x8*)&MAh[fr][ks * 32 + kg * 8];
        bf16x8 al = *(const bf16x8*)&MAl[fr][ks * 32 + kg * 8];
#pragma unroll
        for (int nfi = 0; nfi < CPW; ++nfi) {
            int nf = wv + 4 * nfi;
            if (nf < NF) {
                size_t yo = (size_t)(i_bot0 + nf * 16 + fr) * CH + ks * 32 + kg * 8;
                bf16x8 bh = *(const bf16x8*)(Yh_g + yo);
                bf16x8 bl = *(const bf16x8*)(Yl_g + yo);
                accC[nfi] = MFMA(ah, bh, accC[nfi]);
                accC[nfi] = MFMA(ah, bl, accC[nfi]);
                accC[nfi] = MFMA(al, bh, accC[nfi]);
            }
        }
    }
#pragma unroll
    for (int nfi = 0; nfi < CPW; ++nfi) {
        int nf = wv + 4 * nfi;
        if (nf < NF)
#pragma unroll
            for (int jj = 0; jj < 4; ++jj)
                Cl[kg * 4 + jj][nf * 16 + fr] = accC[nfi][jj];
    }
    __syncthreads();

    // ---- U[i][c] = sum_j C[i][j] MB[j][c]  (16 x 512, K=W); M' = MA - U ----
    f32x4 accU[8];
#pragma unroll
    for (int ni = 0; ni < 8; ++ni)
#pragma unroll
        for (int z = 0; z < 4; ++z) accU[ni][z] = 0.f;

    for (int ks2 = 0; ks2 < W / 32; ++ks2) {
        float a8[8];
#pragma unroll
        for (int j = 0; j < 8; ++j) a8[j] = Cl[fr][ks2 * 32 + kg * 8 + j];
        bf16x8 ah2, al2;
        split8(a8, ah2, al2);
#pragma unroll
        for (int ni = 0; ni < 8; ++ni) {
            int c = (wv * 8 + ni) * 16 + fr;
            size_t mo = (size_t)c * CH + i_bot0 + ks2 * 32 + kg * 8;
            bf16x8 bh = *(const bf16x8*)(Mth_g + mo);
            bf16x8 bl = *(const bf16x8*)(Mtl_g + mo);
            accU[ni] = MFMA(ah2, bh, accU[ni]);
            accU[ni] = MFMA(ah2, bl, accU[ni]);
            accU[ni] = MFMA(al2, bh, accU[ni]);
        }
    }
#pragma unroll
    for (int ni = 0; ni < 8; ++ni) {
        int c = (wv * 8 + ni) * 16 + fr;
#pragma unroll
        for (int jj = 0; jj < 4; ++jj) {
            int il = kg * 4 + jj;
            float ma = bf2f(MAh[il][c]) + bf2f(MAl[il][c]);
            float m2 = ma - accU[ni][jj];
            u16 hu = f2bf(m2);
            MAh[il][c] = hu;
            MAl[il][c] = f2bf(m2 - bf2f(hu));
        }
    }
    __syncthreads();

    // ---- coalesced store back to [c][i] layout ----
    for (int idx = t; idx < 1024; idx += 256) {
        int c = idx >> 1, ch = idx & 1;
        bf16x8 hv, lv;
#pragma unroll
        for (int j = 0; j < 8; ++j) {
            hv[j] = (short)MAh[ch * 8 + j][c];
            lv[j] = (short)MAl[ch * 8 + j][c];
        }
        *(bf16x8*)(Mth_g + (size_t)c * CH + i_top0 + ch * 8) = hv;
        *(bf16x8*)(Mtl_g + (size_t)c * CH + i_top0 + ch * 8) = lv;
    }
}

// ---------------------------------------------------------------------------
// Kernel 3: Qt[g][d][c] (bf16) = [ I - w*M ]^T.  256 blocks, 64(M=c) x 128(N=d)
// tiles, K=512 over reflector index i. A = w[c][i] (k-contig), B = M[i][d]
// from Mt[g][d][i] (k-contig). 4 waves split N.
// ---------------------------------------------------------------------------
__global__ __launch_bounds__(256) void k_qbuild2(const float* __restrict__ w,
                                                 const u16* __restrict__ Mth,
                                                 const u16* __restrict__ Mtl,
                                                 u16* __restrict__ Qt) {
    int t = threadIdx.x, lane = t & 63, wv = t >> 6;
    int fr = lane & 15, kg = lane >> 4;
    int g  = blockIdx.x >> 5;
    int tm = (blockIdx.x >> 2) & 7, tn = blockIdx.x & 3;
    int c0 = tm * 64;
    int d0 = tn * 128 + wv * 32;

    const float* wg = w + (size_t)g * CH * CH;
    const u16* Mth_g = Mth + (size_t)g * CH * CH;
    const u16* Mtl_g = Mtl + (size_t)g * CH * CH;
    u16* Qt_g = Qt + (size_t)g * CH * CH;

    f32x4 acc[4][2];
#pragma unroll
    for (int mi = 0; mi < 4; ++mi)
#pragma unroll
        for (int ni = 0; ni < 2; ++ni)
#pragma unroll
            for (int z = 0; z < 4; ++z) acc[mi][ni][z] = 0.f;

    for (int ks = 0; ks < 16; ++ks) {
        bf16x8 ah[4], al[4], bh[2], bl[2];
#pragma unroll
        for (int mi = 0; mi < 4; ++mi) {
            const float* src = wg + (size_t)(c0 + mi * 16 + fr) * CH + ks * 32 + kg * 8;
            float4 v0 = *(const float4*)src;
            float4 v1 = *(const float4*)(src + 4);
            float a8[8] = {v0.x, v0.y, v0.z, v0.w, v1.x, v1.y, v1.z, v1.w};
            split8(a8, ah[mi], al[mi]);
        }
#pragma unroll
        for (int ni = 0; ni < 2; ++ni) {
            size_t mo = (size_t)(d0 + ni * 16 + fr) * CH + ks * 32 + kg * 8;
            bh[ni] = *(const bf16x8*)(Mth_g + mo);
            bl[ni] = *(const bf16x8*)(Mtl_g + mo);
        }
#pragma unroll
        for (int mi = 0; mi < 4; ++mi)
#pragma unroll
            for (int ni = 0; ni < 2; ++ni) {
                acc[mi][ni] = MFMA(ah[mi], bh[ni], acc[mi][ni]);
                acc[mi][ni] = MFMA(ah[mi], bl[ni], acc[mi][ni]);
                acc[mi][ni] = MFMA(al[mi], bh[ni], acc[mi][ni]);
            }
    }
#pragma unroll
    for (int mi = 0; mi < 4; ++mi)
#pragma unroll
        for (int ni = 0; ni < 2; ++ni) {
            int cb = c0 + mi * 16 + kg * 4;
            int d  = d0 + ni * 16 + fr;
            ushort4 h4;
            h4.x = f2bf(((cb + 0 == d) ? 1.0f : 0.0f) - acc[mi][ni][0]);
            h4.y = f2bf(((cb + 1 == d) ? 1.0f : 0.0f) - acc[mi][ni][1]);
            h4.z = f2bf(((cb + 2 == d) ? 1.0f : 0.0f) - acc[mi][ni][2]);
            h4.w = f2bf(((cb + 3 == d) ? 1.0f : 0.0f) - acc[mi][ni][3]);
            *(ushort4*)(Qt_g + (size_t)d * CH + cb) = h4;
        }
}

// ---------------------------------------------------------------------------
// Kernel 4: out[g] = x[g] (4096x512) @ Q[g].  A = x fp32 (convert in staging),
// B = Qt bf16 [n][k] (vector loads). 128x128 tiles, BK=32, 4 waves 2x2.
// ---------------------------------------------------------------------------
#define BM 128
#define BN 128
#define BK 32
#define LDP 40   // padded LDS row (ushorts)

__global__ __launch_bounds__(256) void k_gemm(const float* __restrict__ x,
                                              const u16* __restrict__ Qt,
                                              float* __restrict__ out) {
    __shared__ u16 Al[BM * LDP];
    __shared__ u16 Bl[BN * LDP];

    int bid = blockIdx.x;
    int g  = bid >> 7;
    int tn = (bid >> 5) & 3;
    int tm = bid & 31;

    int t    = threadIdx.x;
    int lane = t & 63;
    int w    = t >> 6;
    int wr   = w >> 1, wc = w & 1;

    const float* xg = x + (size_t)g * BS * CH + (size_t)tm * BM * CH;
    const u16* Qtg = Qt + (size_t)g * CH * CH + (size_t)tn * BN * CH;
    float* og = out + (size_t)g * BS * CH + (size_t)tm * BM * CH + (size_t)tn * BN;

    f32x4 acc[4][4];
#pragma unroll
    for (int mi = 0; mi < 4; ++mi)
#pragma unroll
        for (int ni = 0; ni < 4; ++ni)
#pragma unroll
            for (int z = 0; z < 4; ++z) acc[mi][ni][z] = 0.f;

    int a_k4 = t & 7;
    int a_r  = t >> 3;
    int b_n  = t & 127;
    int b_kh = t >> 7;

    int fr = lane & 15, kg = lane >> 4;

    for (int ks = 0; ks < CH / BK; ++ks) {
        int k0 = ks * BK;
        __syncthreads();
        // ---- stage A: x tile (128 x 32) fp32 -> bf16 ----
#pragma unroll
        for (int rr = 0; rr < 4; ++rr) {
            int r = a_r + 32 * rr;
            float4 v = *(const float4*)(xg + (size_t)r * CH + k0 + a_k4 * 4);
            ushort4 h;
            h.x = f2bf(v.x); h.y = f2bf(v.y); h.z = f2bf(v.z); h.w = f2bf(v.w);
            *(ushort4*)(&Al[r * LDP + a_k4 * 4]) = h;
        }
        // ---- stage B: Qt rows (128 x 32 bf16), pure vector copies ----
        {
            const u16* src = Qtg + (size_t)b_n * CH + k0 + b_kh * 16;
            u16x8 lo = *(const u16x8*)src;
            u16x8 hi = *(const u16x8*)(src + 8);
            *(u16x8*)(&Bl[b_n * LDP + b_kh * 16]) = lo;
            *(u16x8*)(&Bl[b_n * LDP + b_kh * 16 + 8]) = hi;
        }
        __syncthreads();
        bf16x8 af[4], bfr[4];
#pragma unroll
        for (int mi = 0; mi < 4; ++mi)
            af[mi] = *(const bf16x8*)(&Al[(wr * 64 + mi * 16 + fr) * LDP + kg * 8]);
#pragma unroll
        for (int ni = 0; ni < 4; ++ni)
            bfr[ni] = *(const bf16x8*)(&Bl[(wc * 64 + ni * 16 + fr) * LDP + kg * 8]);
#pragma unroll
        for (int mi = 0; mi < 4; ++mi)
#pragma unroll
            for (int ni = 0; ni < 4; ++ni)
                acc[mi][ni] = MFMA(af[mi], bfr[ni], acc[mi][ni]);
    }

    int rg = lane >> 4;
#pragma unroll
    for (int mi = 0; mi < 4; ++mi)
#pragma unroll
        for (int ni = 0; ni < 4; ++ni)
#pragma unroll
            for (int rj = 0; rj < 4; ++rj) {
                int grow = wr * 64 + mi * 16 + rg * 4 + rj;
                int gcol = wc * 64 + ni * 16 + fr;
                og[(size_t)grow * CH + gcol] = acc[mi][ni][rj];
            }
}

// ---------------------------------------------------------------------------
extern "C" void kernel_launch(void* const* d_in, const int* in_sizes, int n_in,
                              void* d_out, int out_size, void* d_ws, size_t ws_size,
                              hipStream_t stream) {
    const float* x = (const float*)d_in[0];   // (8, 4096, 512)
    const float* w = (const float*)d_in[1];   // (8, 512, 512)
    float* out = (float*)d_out;

    // scratch carved from d_out (64 MiB; dead before k_gemm writes it):
    char* ob = (char*)d_out;
    u16* Yh  = (u16*)ob;                      // [0, 4MB)
    u16* Yl  = (u16*)(ob + (4u  << 20));      // [4, 8)
    u16* Mth = (u16*)(ob + (8u  << 20));      // [8, 12)
    u16* Mtl = (u16*)(ob + (12u << 20));      // [12, 16)
    u16* Qt  = (u16*)d_ws;                    // 4 MB (bf16)

    k_panelprep<<<dim3(128), dim3(256), 0, stream>>>(w, Yh, Yl, Mth, Mtl);
    k_combine<32><<<dim3(128), dim3(256), 0, stream>>>(Yh, Yl, Mth, Mtl);
    k_combine<64><<<dim3(128), dim3(256), 0, stream>>>(Yh, Yl, Mth, Mtl);
    k_combine<128><<<dim3(128), dim3(256), 0, stream>>>(Yh, Yl, Mth, Mtl);
    k_combine<256><<<dim3(128), dim3(256), 0, stream>>>(Yh, Yl, Mth, Mtl);
    k_qbuild2<<<dim3(256), dim3(256), 0, stream>>>(w, Mth, Mtl, Qt);
    k_gemm<<<dim3(1024), dim3(256), 0, stream>>>(x, Qt, out);
}